// Round 7
// baseline (334.138 us; speedup 1.0000x reference)
//
#include <hip/hip_runtime.h>
#include <cstdint>
#include <cstddef>

// ---------------------------------------------------------------------------
// TransformerEncoderBlock: B=2, L=2048, E=1024, H=16, D=64, EXP=4
// bf16 MFMA for all matmuls; f32 residual path; exact-erf GELU.
// ---------------------------------------------------------------------------

typedef __bf16 bht;
typedef __attribute__((ext_vector_type(8))) __bf16 bf16x8;
typedef __attribute__((ext_vector_type(4))) __bf16 bf16x4;
typedef __attribute__((ext_vector_type(4))) float f32x4;
typedef __attribute__((ext_vector_type(4))) short short4v;

#define B_ 2
#define L_ 2048
#define E_ 1024
#define H_ 16
#define D_ 64
#define ROWS_ (B_ * L_)   // 4096

// (1/sqrt(E)) * log2(e) folded into Q at the QKV epilogue
#define QSCALE_ 0.045084441f

__device__ __forceinline__ void glds16(const void* g, void* l) {
    __builtin_amdgcn_global_load_lds(
        (const __attribute__((address_space(1))) unsigned int*)g,
        (__attribute__((address_space(3))) unsigned int*)l, 16, 0, 0);
}

__device__ __forceinline__ short4v as_s4(bf16x4 v) {
    return __builtin_bit_cast(short4v, v);
}

__device__ __forceinline__ float fast_exp2(float x) {
#if __has_builtin(__builtin_amdgcn_exp2f)
    return __builtin_amdgcn_exp2f(x);   // raw v_exp_f32, skip ocml denorm fixup
#else
    return exp2f(x);
#endif
}

// ---------------------------------------------------------------------------
// Transpose + cast f32 [R][C] -> bf16 [C][R]
// ---------------------------------------------------------------------------
__global__ __launch_bounds__(256)
void transpose_cast(const float* __restrict__ in, bht* __restrict__ out, int R, int C) {
    __shared__ float tile[32][33];
    const int bx = blockIdx.x * 32;  // col base
    const int by = blockIdx.y * 32;  // row base
    const int tx = threadIdx.x, ty = threadIdx.y;  // 32 x 8
    #pragma unroll
    for (int i = 0; i < 32; i += 8)
        tile[ty + i][tx] = in[(size_t)(by + ty + i) * C + bx + tx];
    __syncthreads();
    #pragma unroll
    for (int i = 0; i < 32; i += 8)
        out[(size_t)(bx + ty + i) * R + by + tx] = (bht)tile[tx][ty + i];
}

// ---------------------------------------------------------------------------
// LayerNorm: f32 [4096][1024] -> bf16 [4096][1024]
// ---------------------------------------------------------------------------
__global__ __launch_bounds__(256)
void ln_kernel(const float* __restrict__ x, const float* __restrict__ g,
               const float* __restrict__ b, bht* __restrict__ out) {
    const int row = blockIdx.x, t = threadIdx.x;
    const float4 v = ((const float4*)(x + (size_t)row * E_))[t];
    float s  = v.x + v.y + v.z + v.w;
    float ss = v.x*v.x + v.y*v.y + v.z*v.z + v.w*v.w;
    #pragma unroll
    for (int off = 32; off > 0; off >>= 1) {
        s  += __shfl_down(s, off);
        ss += __shfl_down(ss, off);
    }
    __shared__ float red[8];
    const int wave = t >> 6, lane = t & 63;
    if (lane == 0) { red[wave] = s; red[4 + wave] = ss; }
    __syncthreads();
    s  = red[0] + red[1] + red[2] + red[3];
    ss = red[4] + red[5] + red[6] + red[7];
    const float mean = s * (1.0f / (float)E_);
    const float var  = ss * (1.0f / (float)E_) - mean * mean;
    const float rstd = rsqrtf(var + 1e-5f);
    const float4 gv = ((const float4*)g)[t];
    const float4 bv = ((const float4*)b)[t];
    bf16x4 o;
    o.x = (bht)((v.x - mean) * rstd * gv.x + bv.x);
    o.y = (bht)((v.y - mean) * rstd * gv.y + bv.y);
    o.z = (bht)((v.z - mean) * rstd * gv.z + bv.z);
    o.w = (bht)((v.w - mean) * rstd * gv.w + bv.w);
    *(bf16x4*)(out + (size_t)row * E_ + t * 4) = o;
}

enum { EPI_QKV = 0, EPI_RESID = 1, EPI_GELU = 2 };

// ---------------------------------------------------------------------------
// GEMM 256x256, m201-style 4-phase/K-tile schedule (T3+T4+T5).
// BK=64 K-tiles double-buffered by parity: LDS = 2 sides x
// {A_kk0,B_kk0,A_kk1,B_kk1} x 16KB = 128 KB (1 block/CU structural:
// acc[8][4]=128 f32/wave forbids more — round-5 spill lesson).
// Per phase: {ds_read 4 or 8 x b128 -> stage 1 half (2 glds16) -> barrier ->
// lgkmcnt(0) -> setprio(1) -> 16 MFMA -> setprio(0) -> barrier}.
// Phases: ph1 kk0/m0-3 (+B kk0), ph2 kk0/m4-7, ph3 kk1/m0-3 (+B kk1),
// ph4 kk1/m4-7.  Stage stream per tile t: {A_kk0,B_kk0,A_kk1,B_kk1}(t+1)
// at ph1..ph4.  Counted-vmcnt ledger: kk1(t) deadline = ph2-end, kk0(t+1)
// deadline = ph4-end; at both waits exactly the 4 newest loads (not yet
// needed) remain -> vmcnt(4); vmcnt(0) only in the last tile.
// LDS conflicts: 32-col (64B) half-rows are read in FULL per phase (4 quads
// = 4 chunks = whole row) -> chunk=quad is a per-row bijection ->
// structurally conflict-free; NO swizzle on either side (G21).
// Numerics: identical K-order to the previous BK=32 loop.
// ---------------------------------------------------------------------------
template <int EPI>
__global__ __launch_bounds__(512, 2)
void gemm256(const bht* __restrict__ A, const bht* __restrict__ Bt,
             const float* __restrict__ bias, void* __restrict__ outp,
             bht* __restrict__ qo, bht* __restrict__ ko, bht* __restrict__ vto,
             int M, int N, int K) {
    __shared__ __align__(16) char smem_[131072];  // 2 x 64KB sides; Vtile overlay
    const int t = threadIdx.x;                    // 0..511
    const int lane = t & 63, wave = t >> 6;       // 8 waves
    const int lane15 = lane & 15, quad = lane >> 4;
    const int waveM = wave >> 2, waveN = wave & 3;  // 2 x 4
    const int bm = blockIdx.y * 256, bn = blockIdx.x * 256;

    f32x4 acc[8][4];
    #pragma unroll
    for (int i = 0; i < 8; ++i)
        #pragma unroll
        for (int j = 0; j < 4; ++j)
            acc[i][j] = f32x4{0.f, 0.f, 0.f, 0.f};

    // frag-read offsets within a 16KB half ([256 rows][32 cols] bf16, linear):
    // chunk = quad (full-row bijection, conflict-free).  +m*512 / +n*512.
    const int aoff = (waveM * 128 + lane15) * 32 + quad * 8;
    const int boff = (waveN * 64 + lane15) * 32 + quad * 8;

    // stage one half (part 0:A_kk0 1:B_kk0 2:A_kk1 3:B_kk1) of K-tile t2
    auto stage = [&](int t2, int part) {
        const bht* src = (part & 1) ? Bt : A;
        const int rb = (part & 1) ? bn : bm;
        const int kc = t2 * 64 + (part >> 1) * 32;
        char* dst = smem_ + (size_t)(t2 & 1) * 65536 + (size_t)part * 16384;
        #pragma unroll
        for (int i = 0; i < 2; ++i) {
            const int g = i * 512 + t;            // 0..1023 chunks of 16B
            glds16(src + (size_t)(rb + (g >> 2)) * K + kc + (g & 3) * 8,
                   dst + (size_t)g * 16);
        }
    };

    const int NT = K >> 6;                        // 64-wide K-tiles
    // prologue: tile 0 fully staged; kk0 landed, kk1 (4 loads) in flight
    stage(0, 0); stage(0, 1); stage(0, 2); stage(0, 3);
    asm volatile("s_waitcnt vmcnt(4)" ::: "memory");
    __builtin_amdgcn_s_barrier();

    for (int t2 = 0; t2 < NT; ++t2) {
        const bool nx = (t2 + 1 < NT);
        const bht* Ah0 = (const bht*)(smem_ + (size_t)(t2 & 1) * 65536);
        const bht* Bh0 = Ah0 + 8192;    // +16384 B
        const bht* Ah1 = Ah0 + 16384;   // +32768 B
        const bht* Bh1 = Ah0 + 24576;   // +49152 B

        bf16x8 af[4], bf[4];
        // ---- ph1: kk0, m0-3 (+B kk0) --------------------------------------
        #pragma unroll
        for (int m = 0; m < 4; ++m) af[m] = *(const bf16x8*)(Ah0 + aoff + m * 512);
        #pragma unroll
        for (int n = 0; n < 4; ++n) bf[n] = *(const bf16x8*)(Bh0 + boff + n * 512);
        if (nx) stage(t2 + 1, 0);
        __builtin_amdgcn_s_barrier();
        asm volatile("s_waitcnt lgkmcnt(0)" ::: "memory");
        __builtin_amdgcn_s_setprio(1);
        #pragma unroll
        for (int m = 0; m < 4; ++m)
            #pragma unroll
            for (int n = 0; n < 4; ++n)
                acc[m][n] = __builtin_amdgcn_mfma_f32_16x16x32_bf16(af[m], bf[n], acc[m][n], 0, 0, 0);
        __builtin_amdgcn_s_setprio(0);
        __builtin_amdgcn_s_barrier();

        // ---- ph2: kk0, m4-7 ----------------------------------------------
        #pragma unroll
        for (int m = 0; m < 4; ++m) af[m] = *(const bf16x8*)(Ah0 + aoff + (m + 4) * 512);
        if (nx) stage(t2 + 1, 1);
        __builtin_amdgcn_s_barrier();
        asm volatile("s_waitcnt lgkmcnt(0)" ::: "memory");
        __builtin_amdgcn_s_setprio(1);
        #pragma unroll
        for (int m = 0; m < 4; ++m)
            #pragma unroll
            for (int n = 0; n < 4; ++n)
                acc[m + 4][n] = __builtin_amdgcn_mfma_f32_16x16x32_bf16(af[m], bf[n], acc[m + 4][n], 0, 0, 0);
        __builtin_amdgcn_s_setprio(0);
        // kk1(t2) must be resident for ph3; allowed in flight: the 4 loads
        // issued at ph1/ph2 (kk0 halves of t2+1)
        if (nx) asm volatile("s_waitcnt vmcnt(4)" ::: "memory");
        else    asm volatile("s_waitcnt vmcnt(0)" ::: "memory");
        __builtin_amdgcn_s_barrier();

        // ---- ph3: kk1, m0-3 (+B kk1) --------------------------------------
        #pragma unroll
        for (int m = 0; m < 4; ++m) af[m] = *(const bf16x8*)(Ah1 + aoff + m * 512);
        #pragma unroll
        for (int n = 0; n < 4; ++n) bf[n] = *(const bf16x8*)(Bh1 + boff + n * 512);
        if (nx) stage(t2 + 1, 2);
        __builtin_amdgcn_s_barrier();
        asm volatile("s_waitcnt lgkmcnt(0)" ::: "memory");
        __builtin_amdgcn_s_setprio(1);
        #pragma unroll
        for (int m = 0; m < 4; ++m)
            #pragma unroll
            for (int n = 0; n < 4; ++n)
                acc[m][n] = __builtin_amdgcn_mfma_f32_16x16x32_bf16(af[m], bf[n], acc[m][n], 0, 0, 0);
        __builtin_amdgcn_s_setprio(0);
        __builtin_amdgcn_s_barrier();

        // ---- ph4: kk1, m4-7 ----------------------------------------------
        #pragma unroll
        for (int m = 0; m < 4; ++m) af[m] = *(const bf16x8*)(Ah1 + aoff + (m + 4) * 512);
        if (nx) stage(t2 + 1, 3);
        __builtin_amdgcn_s_barrier();
        asm volatile("s_waitcnt lgkmcnt(0)" ::: "memory");
        __builtin_amdgcn_s_setprio(1);
        #pragma unroll
        for (int m = 0; m < 4; ++m)
            #pragma unroll
            for (int n = 0; n < 4; ++n)
                acc[m + 4][n] = __builtin_amdgcn_mfma_f32_16x16x32_bf16(af[m], bf[n], acc[m + 4][n], 0, 0, 0);
        __builtin_amdgcn_s_setprio(0);
        // kk0(t2+1) must be resident for next ph1; allowed in flight: the 4
        // loads issued at ph3/ph4 (kk1 halves of t2+1)
        if (nx) asm volatile("s_waitcnt vmcnt(4)" ::: "memory");
        __builtin_amdgcn_s_barrier();
    }

    // ---- epilogue.  C/D layout: col = lane&15, row = quad*4 + reg ----------
    if constexpr (EPI == EPI_GELU) {
        #pragma unroll
        for (int m = 0; m < 8; ++m) {
            const int row0 = bm + waveM * 128 + m * 16 + quad * 4;
            #pragma unroll
            for (int n = 0; n < 4; ++n) {
                const int col = bn + waveN * 64 + n * 16 + lane15;
                #pragma unroll
                for (int r = 0; r < 4; ++r) {
                    float v = acc[m][n][r] + bias[col];
                    v = 0.5f * v * (1.0f + erff(v * 0.70710678118654752f));
                    ((bht*)outp)[(size_t)(row0 + r) * N + col] = (bht)v;
                }
            }
        }
    } else {  // EPI_QKV
        const int b = bm >> 11, l0 = bm & 2047;
        if (bn >= 2048) {
            // V block: 2-pass transpose via LDS overlay (safe after final
            // barrier; no glds16 outstanding).  Store Vt [bh][d][l] coalesced,
            // with the attn bank-conflict half-swap for (d>>3)&1==1 rows.
            bht* Vtile = (bht*)smem_;   // [128][264] = 67.6 KB
            #pragma unroll
            for (int h = 0; h < 2; ++h) {
                if ((waveN >> 1) == h) {
                    #pragma unroll
                    for (int m = 0; m < 8; ++m) {
                        const int rl0 = waveM * 128 + m * 16 + quad * 4;
                        #pragma unroll
                        for (int n = 0; n < 4; ++n) {
                            const int c = (waveN & 1) * 64 + n * 16 + lane15;
                            #pragma unroll
                            for (int r = 0; r < 4; ++r)
                                Vtile[(size_t)c * 264 + rl0 + r] = (bht)acc[m][n][r];
                        }
                    }
                }
                __syncthreads();
                #pragma unroll
                for (int it = 0; it < 4; ++it) {
                    const int c2 = it * 32 + (t >> 4);          // 0..127
                    const int cg = (bn - 2048) + h * 128 + c2;  // global V col
                    const int hh = cg >> 6, d = cg & 63;
                    const int bh2 = b * H_ + hh;
                    #pragma unroll
                    for (int half2 = 0; half2 < 2; ++half2) {
                        const int ch = (t & 15) + 16 * half2;   // 0..31
                        bf16x8 vv = *(const bf16x8*)(Vtile + (size_t)c2 * 264 + ch * 8);
                        if (d & 8)
                            vv = __builtin_shufflevector(vv, vv, 4, 5, 6, 7, 0, 1, 2, 3);
                        *(bf16x8*)(vto + ((size_t)bh2 * D_ + d) * L_ + l0 + ch * 8) = vv;
                    }
                }
                __syncthreads();
            }
        } else {
            // Q or K block: direct scatter [bh][l][d] (32B coalesced runs)
            #pragma unroll
            for (int m = 0; m < 8; ++m) {
                const int row0 = bm + waveM * 128 + m * 16 + quad * 4;
                #pragma unroll
                for (int n = 0; n < 4; ++n) {
                    const int col = bn + waveN * 64 + n * 16 + lane15;
                    const int seg = col >> 10;        // 0=q,1=k
                    const int c = col & 1023;
                    const int hh = c >> 6, d = c & 63;
                    #pragma unroll
                    for (int r = 0; r < 4; ++r) {
                        const int mrow = row0 + r;
                        const int bb = mrow >> 11, l = mrow & 2047;
                        const int bh2 = bb * H_ + hh;
                        const float v = acc[m][n][r];
                        if (seg == 0)
                            qo[((size_t)bh2 * L_ + l) * D_ + d] = (bht)(v * QSCALE_);
                        else
                            ko[((size_t)bh2 * L_ + l) * D_ + d] = (bht)v;
                    }
                }
            }
        }
    }
    (void)M;
}

// ---------------------------------------------------------------------------
// GEMM 64Mx128N pipelined (T3+T4+T5+T1) for the N=1024 GEMMs (proj, FFN2).
// Grid 8x64 = 512 blocks.  Double-buffered LDS (48 KB),
// stage(s+1) issued BEFORE the wait on stage(s): main-loop wait is vmcnt(6),
// vmcnt(0) only at the last step.  No explicit lgkm drain (compiler counts).
// XCD-chunked block remap (bijective).
// ---------------------------------------------------------------------------
template <int EPI>
__global__ __launch_bounds__(256)
void gemm_pipe64(const bht* __restrict__ A, const bht* __restrict__ Bt,
                 const float* __restrict__ bias, const float* __restrict__ resid,
                 void* __restrict__ outp, int M, int N, int K) {
    __shared__ __align__(16) char smem_[49152];   // 2 x (As 8K + Bs 16K)
    const int t = threadIdx.x;
    const int lane = t & 63, wave = t >> 6;
    const int lane15 = lane & 15, quad = lane >> 4;
    const int waveM = wave >> 1, waveN = wave & 1;

    // XCD-chunked remap (requires gridDim.x == 8, gridDim.y % 8 == 0):
    const int flat = blockIdx.y * gridDim.x + blockIdx.x;
    const int xcd = flat & 7;
    const int w = flat >> 3;                         // 0..63
    const int bm = (xcd * (gridDim.y >> 3) + (w >> 3)) * 64;
    const int bn = (w & 7) * 128;

    f32x4 acc[2][4];
    #pragma unroll
    for (int i = 0; i < 2; ++i)
        #pragma unroll
        for (int j = 0; j < 4; ++j)
            acc[i][j] = f32x4{0.f, 0.f, 0.f, 0.f};

    const int swz = lane15 & 7;

    // stage K-step s into buffer bufi: A 512 chunks (2/thr) + B 1024 (4/thr)
    auto stage = [&](int s, int bufi) {
        const int k0 = s * 64;
        char* base = smem_ + (size_t)bufi * 24576;
        #pragma unroll
        for (int i = 0; i < 2; ++i) {
            const int g = i * 256 + t;
            const int row = g >> 3;
            const int col = ((g & 7) ^ (row & 7)) * 8;
            glds16(A + (size_t)(bm + row) * K + k0 + col, base + (size_t)g * 16);
        }
        #pragma unroll
        for (int i = 0; i < 4; ++i) {
            const int g = i * 256 + t;
            const int row = g >> 3;
            const int col = ((g & 7) ^ (row & 7)) * 8;
            glds16(Bt + (size_t)(bn + row) * K + k0 + col, base + 8192 + (size_t)g * 16);
        }
    };

    const int NT = K >> 6;
    stage(0, 0);
    for (int s = 0; s < NT; ++s) {
        if (s + 1 < NT) {
            stage(s + 1, (s + 1) & 1);
            asm volatile("s_waitcnt vmcnt(6)" ::: "memory");
        } else {
            asm volatile("s_waitcnt vmcnt(0)" ::: "memory");
        }
        __builtin_amdgcn_s_barrier();          // all waves' stage(s) landed
        asm volatile("" ::: "memory");

        const bht* As = (const bht*)(smem_ + (size_t)(s & 1) * 24576);
        const bht* Bs = (const bht*)(smem_ + (size_t)(s & 1) * 24576 + 8192);
        __builtin_amdgcn_s_setprio(1);
        #pragma unroll
        for (int kk = 0; kk < 2; ++kk) {
            const int pc = ((kk * 4 + quad) ^ swz) * 8;
            bf16x8 bfv[4];
            #pragma unroll
            for (int j = 0; j < 4; ++j)
                bfv[j] = *(const bf16x8*)(Bs + (waveN * 64 + j * 16 + lane15) * 64 + pc);
            #pragma unroll
            for (int i = 0; i < 2; ++i) {
                const bf16x8 afi = *(const bf16x8*)(As + (waveM * 32 + i * 16 + lane15) * 64 + pc);
                #pragma unroll
                for (int j = 0; j < 4; ++j)
                    acc[i][j] = __builtin_amdgcn_mfma_f32_16x16x32_bf16(afi, bfv[j], acc[i][j], 0, 0, 0);
            }
        }
        __builtin_amdgcn_s_setprio(0);
        __builtin_amdgcn_s_barrier();          // buffer-reuse fence (no vm drain)
        asm volatile("" ::: "memory");
    }

    #pragma unroll
    for (int i = 0; i < 2; ++i) {
        const int row0 = bm + waveM * 32 + i * 16 + quad * 4;
        #pragma unroll
        for (int j = 0; j < 4; ++j) {
            const int col = bn + waveN * 64 + j * 16 + lane15;
            #pragma unroll
            for (int r = 0; r < 4; ++r) {
                const int m = row0 + r;
                float v = acc[i][j][r];
                if (EPI == EPI_RESID) {
                    ((float*)outp)[(size_t)m * N + col] =
                        v + bias[col] + resid[(size_t)m * N + col];
                } else {  // EPI_GELU
                    v += bias[col];
                    v = 0.5f * v * (1.0f + erff(v * 0.70710678118654752f));
                    ((bht*)outp)[(size_t)m * N + col] = (bht)v;
                }
            }
        }
    }
}

// ---------------------------------------------------------------------------
// Flash attention v7: counted-vmcnt split-stage pipeline + raw v_exp_f32.
// 3 raw barriers/iter, vmcnt never drained with nothing overlapped.
// Vs bank conflicts fixed via global half-swap (conflicts == 0, round-1).
// ---------------------------------------------------------------------------
#define KT_ 128
#define NT_ (L_ / KT_)

__global__ __launch_bounds__(256)
void attn_kernel(const bht* __restrict__ Q, const bht* __restrict__ Kb,
                 const bht* __restrict__ Vt, bht* __restrict__ O) {
    __shared__ __align__(16) bht Ks[KT_ * 64];   // [key][d], 16B chunks ^ (row&7)
    __shared__ __align__(16) bht Vs[64 * KT_];   // [d][key], 16B chunks ^ (row&7)
    __shared__ float Ls[4][16];
    const int t = threadIdx.x;            // 0..255
    const int lane = t & 63, wave = t >> 6;
    const int lane15 = lane & 15, quad = lane >> 4;
    const int bh = blockIdx.x, qt = blockIdx.y;   // bh on x: same head -> same XCD

    const bht* Qh = Q  + (size_t)bh * L_ * D_;
    const bht* Kh = Kb + (size_t)bh * L_ * D_;
    const bht* Vh = Vt + (size_t)bh * D_ * L_;

    const int q0 = qt * 64 + wave * 16;

    // Hoisted Q B-fragments (direct global, one-time): 2 d-chunks, 16B/lane
    bf16x8 aq[2];
    #pragma unroll
    for (int kc = 0; kc < 2; ++kc)
        aq[kc] = *(const bf16x8*)(Qh + (size_t)(q0 + lane15) * D_ + kc * 32 + quad * 8);

    f32x4 o_acc[4];
    #pragma unroll
    for (int db = 0; db < 4; ++db) o_acc[db] = f32x4{0.f, 0.f, 0.f, 0.f};
    float l_sum = 0.f;

    // K fragment-read swizzle (rows are 16n+lane15 -> swizzle = lane15&7)
    const int pc0 = (quad ^ (lane15 & 7)) * 8;
    const int pc1 = pc0 ^ 32;
    // Vs half-select: logical half (quad&1) ^ global store-side swap ((d>>3)&1)
    const int vhalf4 = ((quad & 1) ^ ((lane15 >> 3) & 1)) * 4;

    auto stageK = [&](int kt2) {
        const int key0 = kt2 * KT_;
        #pragma unroll
        for (int i = 0; i < 4; ++i) {
            const int g = i * 256 + t;
            const int krow = g >> 3;
            const int ksc = ((g & 7) ^ (krow & 7)) * 8;
            glds16(Kh + (size_t)(key0 + krow) * D_ + ksc, (char*)Ks + (size_t)g * 16);
        }
    };
    auto stageV = [&](int kt2) {
        const int key0 = kt2 * KT_;
        #pragma unroll
        for (int i = 0; i < 4; ++i) {
            const int g = i * 256 + t;
            const int vrow = g >> 4;
            const int vsc = ((g & 15) ^ (vrow & 7)) * 8;
            glds16(Vh + (size_t)vrow * L_ + key0 + vsc, (char*)Vs + (size_t)g * 16);
        }
    };

    // prologue: K(0) then V(0) in flight (order matters for counted waits)
    stageK(0);
    stageV(0);

    for (int kt = 0; kt < NT_; ++kt) {
        // K(kt) complete (oldest 4+); V(kt) may still be outstanding (<=4)
        asm volatile("s_waitcnt vmcnt(4) lgkmcnt(0)" ::: "memory");
        __builtin_amdgcn_s_barrier();

        // ---- phase A: St = K Q^T over all 8 16-key blocks -> P registers --
        __builtin_amdgcn_s_setprio(1);
        short4v pk[8];
        #pragma unroll
        for (int nb = 0; nb < 8; ++nb) {
            const bf16x8 ak0 = *(const bf16x8*)(Ks + (nb * 16 + lane15) * 64 + pc0);
            const bf16x8 ak1 = *(const bf16x8*)(Ks + (nb * 16 + lane15) * 64 + pc1);
            f32x4 st = __builtin_amdgcn_mfma_f32_16x16x32_bf16(
                ak0, aq[0], f32x4{0.f, 0.f, 0.f, 0.f}, 0, 0, 0);
            st = __builtin_amdgcn_mfma_f32_16x16x32_bf16(ak1, aq[1], st, 0, 0, 0);
            bf16x4 pkv;
            #pragma unroll
            for (int r = 0; r < 4; ++r) {
                const float pv = fast_exp2(st[r]);
                l_sum += pv;
                pkv[r] = (bht)pv;
            }
            pk[nb] = as_s4(pkv);
        }
        __builtin_amdgcn_s_setprio(0);

        // V(kt) complete; all waves done reading Ks -> safe to restage K
        asm volatile("s_waitcnt vmcnt(0) lgkmcnt(0)" ::: "memory");
        __builtin_amdgcn_s_barrier();
        if (kt + 1 < NT_) stageK(kt + 1);   // in flight under phaseB

        // ---- phase B: PV over Vs ------------------------------------------
        __builtin_amdgcn_s_setprio(1);
        #pragma unroll
        for (int nb = 0; nb < 8; ++nb) {
            #pragma unroll
            for (int db = 0; db < 4; ++db) {
                // logical 8B chunk c8 = nb*4+quad of row (db*16+lane15);
                // physical 16B chunk = (c8>>1) ^ (row&7); half = vhalf4
                const int row = db * 16 + lane15;
                const int c16 = (nb * 2 + (quad >> 1)) ^ (row & 7);
                const bf16x4 bv = *(const bf16x4*)(Vs + row * KT_ + c16 * 8 + vhalf4);
                o_acc[db] = __builtin_amdgcn_mfma_f32_16x16x16bf16_1k(
                    pk[nb], as_s4(bv), o_acc[db], 0, 0, 0);
            }
        }
        __builtin_amdgcn_s_setprio(0);

        // all waves done reading Vs -> safe to restage V (don't drain vmcnt:
        // K(kt+1) stays in flight)
        asm volatile("s_waitcnt lgkmcnt(0)" ::: "memory");
        __builtin_amdgcn_s_barrier();
        if (kt + 1 < NT_) stageV(kt + 1);   // in flight under next phaseA
    }

    // denominators: reduce partial sums across the 4 quads (same q=lane15)
    l_sum += __shfl_xor(l_sum, 16);
    l_sum += __shfl_xor(l_sum, 32);
    Ls[wave][lane15] = l_sum;
    asm volatile("s_waitcnt lgkmcnt(0)" ::: "memory");

    const int b = bh >> 4, h = bh & 15;
    #pragma unroll
    for (int r = 0; r < 4; ++r) {
        const int l = q0 + quad * 4 + r;
        const float inv = 1.0f / Ls[wave][quad * 4 + r];
        #pragma unroll
        for (int db = 0; db < 4; ++db)
            O[((size_t)b * L_ + l) * E_ + h * 64 + db * 16 + lane15] =
                (bht)(o_acc[db][r] * inv);
    }
}

// ---------------------------------------------------------------------------
// Launch
// ---------------------------------------------------------------------------
extern "C" void kernel_launch(void* const* d_in, const int* in_sizes, int n_in,
                              void* d_out, int out_size, void* d_ws, size_t ws_size,
                              hipStream_t stream) {
    const float* x      = (const float*)d_in[0];
    const float* ln1_g  = (const float*)d_in[1];
    const float* ln1_b  = (const float*)d_in[2];
    const float* W_qkv  = (const float*)d_in[3];
    const float* W_proj = (const float*)d_in[4];
    const float* b_proj = (const float*)d_in[5];
    const float* ln2_g  = (const float*)d_in[6];
    const float* ln2_b  = (const float*)d_in[7];
    const float* W1     = (const float*)d_in[8];
    const float* b1     = (const float*)d_in[9];
    const float* W2     = (const float*)d_in[10];
    const float* b2     = (const float*)d_in[11];
    float* out = (float*)d_out;

    char* ws = (char*)d_ws;
    auto alloc = [&](size_t bytes) {
        char* p = ws;
        ws += (bytes + 255) & ~(size_t)255;
        return p;
    };
    bht*   WqkvT  = (bht*)alloc((size_t)3072 * 1024 * 2);   // [3E][E]
    bht*   WprojT = (bht*)alloc((size_t)1024 * 1024 * 2);   // [E][E]
    bht*   W1T    = (bht*)alloc((size_t)4096 * 1024 * 2);   // [4E][E]
    bht*   W2T    = (bht*)alloc((size_t)1024 * 4096 * 2);   // [E][4E]
    bht*   hb     = (bht*)alloc((size_t)ROWS_ * E_ * 2);    // LN1 out; reused as LN2 out
    float* x1     = (float*)alloc((size_t)ROWS_ * E_ * 4);  // x + attn proj
    bht*   Qb     = (bht*)alloc((size_t)B_ * H_ * L_ * D_ * 2);
    bht*   Kbuf   = (bht*)alloc((size_t)B_ * H_ * L_ * D_ * 2);
    bht*   Vtb    = (bht*)alloc((size_t)B_ * H_ * D_ * L_ * 2);
    bht*   attno  = (bht*)alloc((size_t)ROWS_ * E_ * 2);
    bht*   ffn1   = Qb;  // reuse 32MB of Q/K/Vt/attno region (free after proj GEMM)

    // 1. Weight transpose+cast
    transpose_cast<<<dim3(3072 / 32, 1024 / 32), dim3(32, 8), 0, stream>>>(W_qkv, WqkvT, 1024, 3072);
    transpose_cast<<<dim3(1024 / 32, 1024 / 32), dim3(32, 8), 0, stream>>>(W_proj, WprojT, 1024, 1024);
    transpose_cast<<<dim3(4096 / 32, 1024 / 32), dim3(32, 8), 0, stream>>>(W1, W1T, 1024, 4096);
    transpose_cast<<<dim3(1024 / 32, 4096 / 32), dim3(32, 8), 0, stream>>>(W2, W2T, 4096, 1024);

    // 2. LN1
    ln_kernel<<<ROWS_, 256, 0, stream>>>(x, ln1_g, ln1_b, hb);

    // 3. QKV GEMM  [4096,1024]x[1024,3072] -> Q/K/Vt scatter (Q pre-scaled)
    gemm256<EPI_QKV><<<dim3(3072 / 256, ROWS_ / 256), 512, 0, stream>>>(
        hb, WqkvT, nullptr, nullptr, Qb, Kbuf, Vtb, ROWS_, 3072, 1024);

    // 4. Attention (bh on grid.x so same-head blocks share an XCD L2)
    attn_kernel<<<dim3(B_ * H_, L_ / 64), 256, 0, stream>>>(Qb, Kbuf, Vtb, attno);

    // 5. Proj GEMM + bias + residual(x) -> x1 (f32)   [pipelined 64x128]
    gemm_pipe64<EPI_RESID><<<dim3(1024 / 128, ROWS_ / 64), 256, 0, stream>>>(
        attno, WprojT, b_proj, x, x1, ROWS_, 1024, 1024);

    // 6. LN2
    ln_kernel<<<ROWS_, 256, 0, stream>>>(x1, ln2_g, ln2_b, hb);

    // 7. FFN1 GEMM + bias + GELU -> ffn1 (bf16)   [256² 4-phase pipelined]
    gemm256<EPI_GELU><<<dim3(4096 / 256, ROWS_ / 256), 512, 0, stream>>>(
        hb, W1T, b1, ffn1, nullptr, nullptr, nullptr, ROWS_, 4096, 1024);

    // 8. FFN2 GEMM + bias + residual(x1) -> out (f32)  [pipelined 64x128]
    gemm_pipe64<EPI_RESID><<<dim3(1024 / 128, ROWS_ / 64), 256, 0, stream>>>(
        ffn1, W2T, b2, x1, out, ROWS_, 1024, 4096);

    (void)in_sizes; (void)n_in; (void)out_size; (void)ws_size;
}

// Round 8
// 323.072 us; speedup vs baseline: 1.0343x; 1.0343x over previous
//
#include <hip/hip_runtime.h>
#include <cstdint>
#include <cstddef>

// ---------------------------------------------------------------------------
// TransformerEncoderBlock: B=2, L=2048, E=1024, H=16, D=64, EXP=4
// bf16 MFMA for all matmuls; f32 residual path; exact-erf GELU.
// ---------------------------------------------------------------------------

typedef __bf16 bht;
typedef __attribute__((ext_vector_type(8))) __bf16 bf16x8;
typedef __attribute__((ext_vector_type(4))) __bf16 bf16x4;
typedef __attribute__((ext_vector_type(4))) float f32x4;
typedef __attribute__((ext_vector_type(4))) short short4v;

#define B_ 2
#define L_ 2048
#define E_ 1024
#define H_ 16
#define D_ 64
#define ROWS_ (B_ * L_)   // 4096

// (1/sqrt(E)) * log2(e) folded into Q at the QKV epilogue
#define QSCALE_ 0.045084441f

__device__ __forceinline__ void glds16(const void* g, void* l) {
    __builtin_amdgcn_global_load_lds(
        (const __attribute__((address_space(1))) unsigned int*)g,
        (__attribute__((address_space(3))) unsigned int*)l, 16, 0, 0);
}

__device__ __forceinline__ short4v as_s4(bf16x4 v) {
    return __builtin_bit_cast(short4v, v);
}

__device__ __forceinline__ float fast_exp2(float x) {
#if __has_builtin(__builtin_amdgcn_exp2f)
    return __builtin_amdgcn_exp2f(x);   // raw v_exp_f32, skip ocml denorm fixup
#else
    return exp2f(x);
#endif
}

// ---------------------------------------------------------------------------
// Transpose + cast f32 [R][C] -> bf16 [C][R]
// ---------------------------------------------------------------------------
__global__ __launch_bounds__(256)
void transpose_cast(const float* __restrict__ in, bht* __restrict__ out, int R, int C) {
    __shared__ float tile[32][33];
    const int bx = blockIdx.x * 32;  // col base
    const int by = blockIdx.y * 32;  // row base
    const int tx = threadIdx.x, ty = threadIdx.y;  // 32 x 8
    #pragma unroll
    for (int i = 0; i < 32; i += 8)
        tile[ty + i][tx] = in[(size_t)(by + ty + i) * C + bx + tx];
    __syncthreads();
    #pragma unroll
    for (int i = 0; i < 32; i += 8)
        out[(size_t)(bx + ty + i) * R + by + tx] = (bht)tile[tx][ty + i];
}

// ---------------------------------------------------------------------------
// LayerNorm: f32 [4096][1024] -> bf16 [4096][1024]
// ---------------------------------------------------------------------------
__global__ __launch_bounds__(256)
void ln_kernel(const float* __restrict__ x, const float* __restrict__ g,
               const float* __restrict__ b, bht* __restrict__ out) {
    const int row = blockIdx.x, t = threadIdx.x;
    const float4 v = ((const float4*)(x + (size_t)row * E_))[t];
    float s  = v.x + v.y + v.z + v.w;
    float ss = v.x*v.x + v.y*v.y + v.z*v.z + v.w*v.w;
    #pragma unroll
    for (int off = 32; off > 0; off >>= 1) {
        s  += __shfl_down(s, off);
        ss += __shfl_down(ss, off);
    }
    __shared__ float red[8];
    const int wave = t >> 6, lane = t & 63;
    if (lane == 0) { red[wave] = s; red[4 + wave] = ss; }
    __syncthreads();
    s  = red[0] + red[1] + red[2] + red[3];
    ss = red[4] + red[5] + red[6] + red[7];
    const float mean = s * (1.0f / (float)E_);
    const float var  = ss * (1.0f / (float)E_) - mean * mean;
    const float rstd = rsqrtf(var + 1e-5f);
    const float4 gv = ((const float4*)g)[t];
    const float4 bv = ((const float4*)b)[t];
    bf16x4 o;
    o.x = (bht)((v.x - mean) * rstd * gv.x + bv.x);
    o.y = (bht)((v.y - mean) * rstd * gv.y + bv.y);
    o.z = (bht)((v.z - mean) * rstd * gv.z + bv.z);
    o.w = (bht)((v.w - mean) * rstd * gv.w + bv.w);
    *(bf16x4*)(out + (size_t)row * E_ + t * 4) = o;
}

enum { EPI_QKV = 0, EPI_RESID = 1, EPI_GELU = 2 };

// ---------------------------------------------------------------------------
// GEMM 256x256, m201-style 4-phase/K-tile schedule (T2+T3+T4+T5).
// BK=64 K-tiles double-buffered by parity: LDS = 2 sides x
// {A_kk0,B_kk0,A_kk1,B_kk1} x 16KB = 128 KB (1 block/CU structural:
// acc[8][4]=128 f32/wave — round-5 spill lesson).
// Per phase: {ds_read 4 or 8 x b128 -> stage 1 half (2 glds16) -> barrier ->
// lgkmcnt(0) -> setprio(1) -> 16 MFMA -> setprio(0) -> barrier}.
// Counted-vmcnt ledger: at each per-tile wait exactly the 4 newest loads
// (not yet needed) remain -> vmcnt(4); vmcnt(0) only in the last tile.
// T2 swizzle (round-6-verified, 0 conflicts on this exact [256][32] layout):
// physical chunk = logical chunk ^ ((row>>1)&3), applied on the GLOBAL
// source (glds16 dest linear, G21) and on frag reads ((row>>1)&3 ==
// ((lane15>>1)&3), per-lane constant).  Round-7's chunk=quad (no XOR) was
// an 8-way conflict (3.1M cycles) — T2 is T3's prerequisite (m198->m201).
// ---------------------------------------------------------------------------
template <int EPI>
__global__ __launch_bounds__(512, 2)
void gemm256(const bht* __restrict__ A, const bht* __restrict__ Bt,
             const float* __restrict__ bias, void* __restrict__ outp,
             bht* __restrict__ qo, bht* __restrict__ ko, bht* __restrict__ vto,
             int M, int N, int K) {
    __shared__ __align__(16) char smem_[131072];  // 2 x 64KB sides; Vtile overlay
    const int t = threadIdx.x;                    // 0..511
    const int lane = t & 63, wave = t >> 6;       // 8 waves
    const int lane15 = lane & 15, quad = lane >> 4;
    const int waveM = wave >> 2, waveN = wave & 3;  // 2 x 4
    const int bm = blockIdx.y * 256, bn = blockIdx.x * 256;

    f32x4 acc[8][4];
    #pragma unroll
    for (int i = 0; i < 8; ++i)
        #pragma unroll
        for (int j = 0; j < 4; ++j)
            acc[i][j] = f32x4{0.f, 0.f, 0.f, 0.f};

    // frag-read offsets within a 16KB half ([256 rows][32 cols] bf16):
    // physical chunk = quad ^ ((lane15>>1)&3)  [T2, round-6-verified]
    const int apc = ((quad ^ ((lane15 >> 1) & 3)) & 3) * 8;
    const int aoff = (waveM * 128 + lane15) * 32 + apc;
    const int boff = (waveN * 64 + lane15) * 32 + apc;

    // stage one half (part 0:A_kk0 1:B_kk0 2:A_kk1 3:B_kk1) of K-tile t2;
    // pre-swizzled global source, linear LDS dest (G21)
    auto stage = [&](int t2, int part) {
        const bht* src = (part & 1) ? Bt : A;
        const int rb = (part & 1) ? bn : bm;
        const int kc = t2 * 64 + (part >> 1) * 32;
        char* dst = smem_ + (size_t)(t2 & 1) * 65536 + (size_t)part * 16384;
        #pragma unroll
        for (int i = 0; i < 2; ++i) {
            const int g = i * 512 + t;            // 0..1023 chunks of 16B
            const int row = g >> 2;
            const int c = ((g & 3) ^ ((row >> 1) & 3)) * 8;
            glds16(src + (size_t)(rb + row) * K + kc + c, dst + (size_t)g * 16);
        }
    };

    const int NT = K >> 6;                        // 64-wide K-tiles
    // prologue: tile 0 fully staged; kk0 landed, kk1 (4 loads) in flight
    stage(0, 0); stage(0, 1); stage(0, 2); stage(0, 3);
    asm volatile("s_waitcnt vmcnt(4)" ::: "memory");
    __builtin_amdgcn_s_barrier();

    for (int t2 = 0; t2 < NT; ++t2) {
        const bool nx = (t2 + 1 < NT);
        const bht* Ah0 = (const bht*)(smem_ + (size_t)(t2 & 1) * 65536);
        const bht* Bh0 = Ah0 + 8192;    // +16384 B
        const bht* Ah1 = Ah0 + 16384;   // +32768 B
        const bht* Bh1 = Ah0 + 24576;   // +49152 B

        bf16x8 af[4], bf[4];
        // ---- ph1: kk0, m0-3 (+B kk0) --------------------------------------
        #pragma unroll
        for (int m = 0; m < 4; ++m) af[m] = *(const bf16x8*)(Ah0 + aoff + m * 512);
        #pragma unroll
        for (int n = 0; n < 4; ++n) bf[n] = *(const bf16x8*)(Bh0 + boff + n * 512);
        if (nx) stage(t2 + 1, 0);
        __builtin_amdgcn_s_barrier();
        asm volatile("s_waitcnt lgkmcnt(0)" ::: "memory");
        __builtin_amdgcn_s_setprio(1);
        #pragma unroll
        for (int m = 0; m < 4; ++m)
            #pragma unroll
            for (int n = 0; n < 4; ++n)
                acc[m][n] = __builtin_amdgcn_mfma_f32_16x16x32_bf16(af[m], bf[n], acc[m][n], 0, 0, 0);
        __builtin_amdgcn_s_setprio(0);
        __builtin_amdgcn_s_barrier();

        // ---- ph2: kk0, m4-7 ----------------------------------------------
        #pragma unroll
        for (int m = 0; m < 4; ++m) af[m] = *(const bf16x8*)(Ah0 + aoff + (m + 4) * 512);
        if (nx) stage(t2 + 1, 1);
        __builtin_amdgcn_s_barrier();
        asm volatile("s_waitcnt lgkmcnt(0)" ::: "memory");
        __builtin_amdgcn_s_setprio(1);
        #pragma unroll
        for (int m = 0; m < 4; ++m)
            #pragma unroll
            for (int n = 0; n < 4; ++n)
                acc[m + 4][n] = __builtin_amdgcn_mfma_f32_16x16x32_bf16(af[m], bf[n], acc[m + 4][n], 0, 0, 0);
        __builtin_amdgcn_s_setprio(0);
        // kk1(t2) must be resident for ph3; allowed in flight: the 4 loads
        // issued at ph1/ph2 (kk0 halves of t2+1)
        if (nx) asm volatile("s_waitcnt vmcnt(4)" ::: "memory");
        else    asm volatile("s_waitcnt vmcnt(0)" ::: "memory");
        __builtin_amdgcn_s_barrier();

        // ---- ph3: kk1, m0-3 (+B kk1) --------------------------------------
        #pragma unroll
        for (int m = 0; m < 4; ++m) af[m] = *(const bf16x8*)(Ah1 + aoff + m * 512);
        #pragma unroll
        for (int n = 0; n < 4; ++n) bf[n] = *(const bf16x8*)(Bh1 + boff + n * 512);
        if (nx) stage(t2 + 1, 2);
        __builtin_amdgcn_s_barrier();
        asm volatile("s_waitcnt lgkmcnt(0)" ::: "memory");
        __builtin_amdgcn_s_setprio(1);
        #pragma unroll
        for (int m = 0; m < 4; ++m)
            #pragma unroll
            for (int n = 0; n < 4; ++n)
                acc[m][n] = __builtin_amdgcn_mfma_f32_16x16x32_bf16(af[m], bf[n], acc[m][n], 0, 0, 0);
        __builtin_amdgcn_s_setprio(0);
        __builtin_amdgcn_s_barrier();

        // ---- ph4: kk1, m4-7 ----------------------------------------------
        #pragma unroll
        for (int m = 0; m < 4; ++m) af[m] = *(const bf16x8*)(Ah1 + aoff + (m + 4) * 512);
        if (nx) stage(t2 + 1, 3);
        __builtin_amdgcn_s_barrier();
        asm volatile("s_waitcnt lgkmcnt(0)" ::: "memory");
        __builtin_amdgcn_s_setprio(1);
        #pragma unroll
        for (int m = 0; m < 4; ++m)
            #pragma unroll
            for (int n = 0; n < 4; ++n)
                acc[m + 4][n] = __builtin_amdgcn_mfma_f32_16x16x32_bf16(af[m], bf[n], acc[m + 4][n], 0, 0, 0);
        __builtin_amdgcn_s_setprio(0);
        // kk0(t2+1) must be resident for next ph1; allowed in flight: the 4
        // loads issued at ph3/ph4 (kk1 halves of t2+1)
        if (nx) asm volatile("s_waitcnt vmcnt(4)" ::: "memory");
        __builtin_amdgcn_s_barrier();
    }

    // ---- epilogue.  C/D layout: col = lane&15, row = quad*4 + reg ----------
    if constexpr (EPI == EPI_GELU) {
        #pragma unroll
        for (int m = 0; m < 8; ++m) {
            const int row0 = bm + waveM * 128 + m * 16 + quad * 4;
            #pragma unroll
            for (int n = 0; n < 4; ++n) {
                const int col = bn + waveN * 64 + n * 16 + lane15;
                #pragma unroll
                for (int r = 0; r < 4; ++r) {
                    float v = acc[m][n][r] + bias[col];
                    v = 0.5f * v * (1.0f + erff(v * 0.70710678118654752f));
                    ((bht*)outp)[(size_t)(row0 + r) * N + col] = (bht)v;
                }
            }
        }
    } else {  // EPI_QKV
        const int b = bm >> 11, l0 = bm & 2047;
        if (bn >= 2048) {
            // V block: 2-pass transpose via LDS overlay (safe after final
            // barrier; no glds16 outstanding).  Store Vt [bh][d][l] coalesced,
            // with the attn bank-conflict half-swap for (d>>3)&1==1 rows.
            bht* Vtile = (bht*)smem_;   // [128][264] = 67.6 KB
            #pragma unroll
            for (int h = 0; h < 2; ++h) {
                if ((waveN >> 1) == h) {
                    #pragma unroll
                    for (int m = 0; m < 8; ++m) {
                        const int rl0 = waveM * 128 + m * 16 + quad * 4;
                        #pragma unroll
                        for (int n = 0; n < 4; ++n) {
                            const int c = (waveN & 1) * 64 + n * 16 + lane15;
                            #pragma unroll
                            for (int r = 0; r < 4; ++r)
                                Vtile[(size_t)c * 264 + rl0 + r] = (bht)acc[m][n][r];
                        }
                    }
                }
                __syncthreads();
                #pragma unroll
                for (int it = 0; it < 4; ++it) {
                    const int c2 = it * 32 + (t >> 4);          // 0..127
                    const int cg = (bn - 2048) + h * 128 + c2;  // global V col
                    const int hh = cg >> 6, d = cg & 63;
                    const int bh2 = b * H_ + hh;
                    #pragma unroll
                    for (int half2 = 0; half2 < 2; ++half2) {
                        const int ch = (t & 15) + 16 * half2;   // 0..31
                        bf16x8 vv = *(const bf16x8*)(Vtile + (size_t)c2 * 264 + ch * 8);
                        if (d & 8)
                            vv = __builtin_shufflevector(vv, vv, 4, 5, 6, 7, 0, 1, 2, 3);
                        *(bf16x8*)(vto + ((size_t)bh2 * D_ + d) * L_ + l0 + ch * 8) = vv;
                    }
                }
                __syncthreads();
            }
        } else {
            // Q or K block: direct scatter [bh][l][d] (32B coalesced runs)
            #pragma unroll
            for (int m = 0; m < 8; ++m) {
                const int row0 = bm + waveM * 128 + m * 16 + quad * 4;
                #pragma unroll
                for (int n = 0; n < 4; ++n) {
                    const int col = bn + waveN * 64 + n * 16 + lane15;
                    const int seg = col >> 10;        // 0=q,1=k
                    const int c = col & 1023;
                    const int hh = c >> 6, d = c & 63;
                    #pragma unroll
                    for (int r = 0; r < 4; ++r) {
                        const int mrow = row0 + r;
                        const int bb = mrow >> 11, l = mrow & 2047;
                        const int bh2 = bb * H_ + hh;
                        const float v = acc[m][n][r];
                        if (seg == 0)
                            qo[((size_t)bh2 * L_ + l) * D_ + d] = (bht)(v * QSCALE_);
                        else
                            ko[((size_t)bh2 * L_ + l) * D_ + d] = (bht)v;
                    }
                }
            }
        }
    }
    (void)M;
}

// ---------------------------------------------------------------------------
// GEMM 64Mx128N pipelined (T3+T4+T5+T1) for the N=1024 GEMMs (proj, FFN2).
// Grid 8x64 = 512 blocks.  Double-buffered LDS (48 KB),
// stage(s+1) issued BEFORE the wait on stage(s): main-loop wait is vmcnt(6),
// vmcnt(0) only at the last step.  No explicit lgkm drain (compiler counts).
// XCD-chunked block remap (bijective).
// ---------------------------------------------------------------------------
template <int EPI>
__global__ __launch_bounds__(256)
void gemm_pipe64(const bht* __restrict__ A, const bht* __restrict__ Bt,
                 const float* __restrict__ bias, const float* __restrict__ resid,
                 void* __restrict__ outp, int M, int N, int K) {
    __shared__ __align__(16) char smem_[49152];   // 2 x (As 8K + Bs 16K)
    const int t = threadIdx.x;
    const int lane = t & 63, wave = t >> 6;
    const int lane15 = lane & 15, quad = lane >> 4;
    const int waveM = wave >> 1, waveN = wave & 1;

    // XCD-chunked remap (requires gridDim.x == 8, gridDim.y % 8 == 0):
    const int flat = blockIdx.y * gridDim.x + blockIdx.x;
    const int xcd = flat & 7;
    const int w = flat >> 3;                         // 0..63
    const int bm = (xcd * (gridDim.y >> 3) + (w >> 3)) * 64;
    const int bn = (w & 7) * 128;

    f32x4 acc[2][4];
    #pragma unroll
    for (int i = 0; i < 2; ++i)
        #pragma unroll
        for (int j = 0; j < 4; ++j)
            acc[i][j] = f32x4{0.f, 0.f, 0.f, 0.f};

    const int swz = lane15 & 7;

    // stage K-step s into buffer bufi: A 512 chunks (2/thr) + B 1024 (4/thr)
    auto stage = [&](int s, int bufi) {
        const int k0 = s * 64;
        char* base = smem_ + (size_t)bufi * 24576;
        #pragma unroll
        for (int i = 0; i < 2; ++i) {
            const int g = i * 256 + t;
            const int row = g >> 3;
            const int col = ((g & 7) ^ (row & 7)) * 8;
            glds16(A + (size_t)(bm + row) * K + k0 + col, base + (size_t)g * 16);
        }
        #pragma unroll
        for (int i = 0; i < 4; ++i) {
            const int g = i * 256 + t;
            const int row = g >> 3;
            const int col = ((g & 7) ^ (row & 7)) * 8;
            glds16(Bt + (size_t)(bn + row) * K + k0 + col, base + 8192 + (size_t)g * 16);
        }
    };

    const int NT = K >> 6;
    stage(0, 0);
    for (int s = 0; s < NT; ++s) {
        if (s + 1 < NT) {
            stage(s + 1, (s + 1) & 1);
            asm volatile("s_waitcnt vmcnt(6)" ::: "memory");
        } else {
            asm volatile("s_waitcnt vmcnt(0)" ::: "memory");
        }
        __builtin_amdgcn_s_barrier();          // all waves' stage(s) landed
        asm volatile("" ::: "memory");

        const bht* As = (const bht*)(smem_ + (size_t)(s & 1) * 24576);
        const bht* Bs = (const bht*)(smem_ + (size_t)(s & 1) * 24576 + 8192);
        __builtin_amdgcn_s_setprio(1);
        #pragma unroll
        for (int kk = 0; kk < 2; ++kk) {
            const int pc = ((kk * 4 + quad) ^ swz) * 8;
            bf16x8 bfv[4];
            #pragma unroll
            for (int j = 0; j < 4; ++j)
                bfv[j] = *(const bf16x8*)(Bs + (waveN * 64 + j * 16 + lane15) * 64 + pc);
            #pragma unroll
            for (int i = 0; i < 2; ++i) {
                const bf16x8 afi = *(const bf16x8*)(As + (waveM * 32 + i * 16 + lane15) * 64 + pc);
                #pragma unroll
                for (int j = 0; j < 4; ++j)
                    acc[i][j] = __builtin_amdgcn_mfma_f32_16x16x32_bf16(afi, bfv[j], acc[i][j], 0, 0, 0);
            }
        }
        __builtin_amdgcn_s_setprio(0);
        __builtin_amdgcn_s_barrier();          // buffer-reuse fence (no vm drain)
        asm volatile("" ::: "memory");
    }

    #pragma unroll
    for (int i = 0; i < 2; ++i) {
        const int row0 = bm + waveM * 32 + i * 16 + quad * 4;
        #pragma unroll
        for (int j = 0; j < 4; ++j) {
            const int col = bn + waveN * 64 + j * 16 + lane15;
            #pragma unroll
            for (int r = 0; r < 4; ++r) {
                const int m = row0 + r;
                float v = acc[i][j][r];
                if (EPI == EPI_RESID) {
                    ((float*)outp)[(size_t)m * N + col] =
                        v + bias[col] + resid[(size_t)m * N + col];
                } else {  // EPI_GELU
                    v += bias[col];
                    v = 0.5f * v * (1.0f + erff(v * 0.70710678118654752f));
                    ((bht*)outp)[(size_t)m * N + col] = (bht)v;
                }
            }
        }
    }
}

// ---------------------------------------------------------------------------
// Flash attention v7: counted-vmcnt split-stage pipeline + raw v_exp_f32.
// 3 raw barriers/iter, vmcnt never drained with nothing overlapped.
// Vs bank conflicts fixed via global half-swap (conflicts == 0, round-1).
// ---------------------------------------------------------------------------
#define KT_ 128
#define NT_ (L_ / KT_)

__global__ __launch_bounds__(256)
void attn_kernel(const bht* __restrict__ Q, const bht* __restrict__ Kb,
                 const bht* __restrict__ Vt, bht* __restrict__ O) {
    __shared__ __align__(16) bht Ks[KT_ * 64];   // [key][d], 16B chunks ^ (row&7)
    __shared__ __align__(16) bht Vs[64 * KT_];   // [d][key], 16B chunks ^ (row&7)
    __shared__ float Ls[4][16];
    const int t = threadIdx.x;            // 0..255
    const int lane = t & 63, wave = t >> 6;
    const int lane15 = lane & 15, quad = lane >> 4;
    const int bh = blockIdx.x, qt = blockIdx.y;   // bh on x: same head -> same XCD

    const bht* Qh = Q  + (size_t)bh * L_ * D_;
    const bht* Kh = Kb + (size_t)bh * L_ * D_;
    const bht* Vh = Vt + (size_t)bh * D_ * L_;

    const int q0 = qt * 64 + wave * 16;

    // Hoisted Q B-fragments (direct global, one-time): 2 d-chunks, 16B/lane
    bf16x8 aq[2];
    #pragma unroll
    for (int kc = 0; kc < 2; ++kc)
        aq[kc] = *(const bf16x8*)(Qh + (size_t)(q0 + lane15) * D_ + kc * 32 + quad * 8);

    f32x4 o_acc[4];
    #pragma unroll
    for (int db = 0; db < 4; ++db) o_acc[db] = f32x4{0.f, 0.f, 0.f, 0.f};
    float l_sum = 0.f;

    // K fragment-read swizzle (rows are 16n+lane15 -> swizzle = lane15&7)
    const int pc0 = (quad ^ (lane15 & 7)) * 8;
    const int pc1 = pc0 ^ 32;
    // Vs half-select: logical half (quad&1) ^ global store-side swap ((d>>3)&1)
    const int vhalf4 = ((quad & 1) ^ ((lane15 >> 3) & 1)) * 4;

    auto stageK = [&](int kt2) {
        const int key0 = kt2 * KT_;
        #pragma unroll
        for (int i = 0; i < 4; ++i) {
            const int g = i * 256 + t;
            const int krow = g >> 3;
            const int ksc = ((g & 7) ^ (krow & 7)) * 8;
            glds16(Kh + (size_t)(key0 + krow) * D_ + ksc, (char*)Ks + (size_t)g * 16);
        }
    };
    auto stageV = [&](int kt2) {
        const int key0 = kt2 * KT_;
        #pragma unroll
        for (int i = 0; i < 4; ++i) {
            const int g = i * 256 + t;
            const int vrow = g >> 4;
            const int vsc = ((g & 15) ^ (vrow & 7)) * 8;
            glds16(Vh + (size_t)vrow * L_ + key0 + vsc, (char*)Vs + (size_t)g * 16);
        }
    };

    // prologue: K(0) then V(0) in flight (order matters for counted waits)
    stageK(0);
    stageV(0);

    for (int kt = 0; kt < NT_; ++kt) {
        // K(kt) complete (oldest 4+); V(kt) may still be outstanding (<=4)
        asm volatile("s_waitcnt vmcnt(4) lgkmcnt(0)" ::: "memory");
        __builtin_amdgcn_s_barrier();

        // ---- phase A: St = K Q^T over all 8 16-key blocks -> P registers --
        __builtin_amdgcn_s_setprio(1);
        short4v pk[8];
        #pragma unroll
        for (int nb = 0; nb < 8; ++nb) {
            const bf16x8 ak0 = *(const bf16x8*)(Ks + (nb * 16 + lane15) * 64 + pc0);
            const bf16x8 ak1 = *(const bf16x8*)(Ks + (nb * 16 + lane15) * 64 + pc1);
            f32x4 st = __builtin_amdgcn_mfma_f32_16x16x32_bf16(
                ak0, aq[0], f32x4{0.f, 0.f, 0.f, 0.f}, 0, 0, 0);
            st = __builtin_amdgcn_mfma_f32_16x16x32_bf16(ak1, aq[1], st, 0, 0, 0);
            bf16x4 pkv;
            #pragma unroll
            for (int r = 0; r < 4; ++r) {
                const float pv = fast_exp2(st[r]);
                l_sum += pv;
                pkv[r] = (bht)pv;
            }
            pk[nb] = as_s4(pkv);
        }
        __builtin_amdgcn_s_setprio(0);

        // V(kt) complete; all waves done reading Ks -> safe to restage K
        asm volatile("s_waitcnt vmcnt(0) lgkmcnt(0)" ::: "memory");
        __builtin_amdgcn_s_barrier();
        if (kt + 1 < NT_) stageK(kt + 1);   // in flight under phaseB

        // ---- phase B: PV over Vs ------------------------------------------
        __builtin_amdgcn_s_setprio(1);
        #pragma unroll
        for (int nb = 0; nb < 8; ++nb) {
            #pragma unroll
            for (int db = 0; db < 4; ++db) {
                // logical 8B chunk c8 = nb*4+quad of row (db*16+lane15);
                // physical 16B chunk = (c8>>1) ^ (row&7); half = vhalf4
                const int row = db * 16 + lane15;
                const int c16 = (nb * 2 + (quad >> 1)) ^ (row & 7);
                const bf16x4 bv = *(const bf16x4*)(Vs + row * KT_ + c16 * 8 + vhalf4);
                o_acc[db] = __builtin_amdgcn_mfma_f32_16x16x16bf16_1k(
                    pk[nb], as_s4(bv), o_acc[db], 0, 0, 0);
            }
        }
        __builtin_amdgcn_s_setprio(0);

        // all waves done reading Vs -> safe to restage V (don't drain vmcnt:
        // K(kt+1) stays in flight)
        asm volatile("s_waitcnt lgkmcnt(0)" ::: "memory");
        __builtin_amdgcn_s_barrier();
        if (kt + 1 < NT_) stageV(kt + 1);   // in flight under next phaseA
    }

    // denominators: reduce partial sums across the 4 quads (same q=lane15)
    l_sum += __shfl_xor(l_sum, 16);
    l_sum += __shfl_xor(l_sum, 32);
    Ls[wave][lane15] = l_sum;
    asm volatile("s_waitcnt lgkmcnt(0)" ::: "memory");

    const int b = bh >> 4, h = bh & 15;
    #pragma unroll
    for (int r = 0; r < 4; ++r) {
        const int l = q0 + quad * 4 + r;
        const float inv = 1.0f / Ls[wave][quad * 4 + r];
        #pragma unroll
        for (int db = 0; db < 4; ++db)
            O[((size_t)b * L_ + l) * E_ + h * 64 + db * 16 + lane15] =
                (bht)(o_acc[db][r] * inv);
    }
}

// ---------------------------------------------------------------------------
// Launch
// ---------------------------------------------------------------------------
extern "C" void kernel_launch(void* const* d_in, const int* in_sizes, int n_in,
                              void* d_out, int out_size, void* d_ws, size_t ws_size,
                              hipStream_t stream) {
    const float* x      = (const float*)d_in[0];
    const float* ln1_g  = (const float*)d_in[1];
    const float* ln1_b  = (const float*)d_in[2];
    const float* W_qkv  = (const float*)d_in[3];
    const float* W_proj = (const float*)d_in[4];
    const float* b_proj = (const float*)d_in[5];
    const float* ln2_g  = (const float*)d_in[6];
    const float* ln2_b  = (const float*)d_in[7];
    const float* W1     = (const float*)d_in[8];
    const float* b1     = (const float*)d_in[9];
    const float* W2     = (const float*)d_in[10];
    const float* b2     = (const float*)d_in[11];
    float* out = (float*)d_out;

    char* ws = (char*)d_ws;
    auto alloc = [&](size_t bytes) {
        char* p = ws;
        ws += (bytes + 255) & ~(size_t)255;
        return p;
    };
    bht*   WqkvT  = (bht*)alloc((size_t)3072 * 1024 * 2);   // [3E][E]
    bht*   WprojT = (bht*)alloc((size_t)1024 * 1024 * 2);   // [E][E]
    bht*   W1T    = (bht*)alloc((size_t)4096 * 1024 * 2);   // [4E][E]
    bht*   W2T    = (bht*)alloc((size_t)1024 * 4096 * 2);   // [E][4E]
    bht*   hb     = (bht*)alloc((size_t)ROWS_ * E_ * 2);    // LN1 out; reused as LN2 out
    float* x1     = (float*)alloc((size_t)ROWS_ * E_ * 4);  // x + attn proj
    bht*   Qb     = (bht*)alloc((size_t)B_ * H_ * L_ * D_ * 2);
    bht*   Kbuf   = (bht*)alloc((size_t)B_ * H_ * L_ * D_ * 2);
    bht*   Vtb    = (bht*)alloc((size_t)B_ * H_ * D_ * L_ * 2);
    bht*   attno  = (bht*)alloc((size_t)ROWS_ * E_ * 2);
    bht*   ffn1   = Qb;  // reuse 32MB of Q/K/Vt/attno region (free after proj GEMM)

    // 1. Weight transpose+cast
    transpose_cast<<<dim3(3072 / 32, 1024 / 32), dim3(32, 8), 0, stream>>>(W_qkv, WqkvT, 1024, 3072);
    transpose_cast<<<dim3(1024 / 32, 1024 / 32), dim3(32, 8), 0, stream>>>(W_proj, WprojT, 1024, 1024);
    transpose_cast<<<dim3(4096 / 32, 1024 / 32), dim3(32, 8), 0, stream>>>(W1, W1T, 1024, 4096);
    transpose_cast<<<dim3(1024 / 32, 4096 / 32), dim3(32, 8), 0, stream>>>(W2, W2T, 4096, 1024);

    // 2. LN1
    ln_kernel<<<ROWS_, 256, 0, stream>>>(x, ln1_g, ln1_b, hb);

    // 3. QKV GEMM  [4096,1024]x[1024,3072] -> Q/K/Vt scatter (Q pre-scaled)
    gemm256<EPI_QKV><<<dim3(3072 / 256, ROWS_ / 256), 512, 0, stream>>>(
        hb, WqkvT, nullptr, nullptr, Qb, Kbuf, Vtb, ROWS_, 3072, 1024);

    // 4. Attention (bh on grid.x so same-head blocks share an XCD L2)
    attn_kernel<<<dim3(B_ * H_, L_ / 64), 256, 0, stream>>>(Qb, Kbuf, Vtb, attno);

    // 5. Proj GEMM + bias + residual(x) -> x1 (f32)   [pipelined 64x128]
    gemm_pipe64<EPI_RESID><<<dim3(1024 / 128, ROWS_ / 64), 256, 0, stream>>>(
        attno, WprojT, b_proj, x, x1, ROWS_, 1024, 1024);

    // 6. LN2
    ln_kernel<<<ROWS_, 256, 0, stream>>>(x1, ln2_g, ln2_b, hb);

    // 7. FFN1 GEMM + bias + GELU -> ffn1 (bf16)   [256² 4-phase + T2 swizzle]
    gemm256<EPI_GELU><<<dim3(4096 / 256, ROWS_ / 256), 512, 0, stream>>>(
        hb, W1T, b1, ffn1, nullptr, nullptr, nullptr, ROWS_, 4096, 1024);

    // 8. FFN2 GEMM + bias + residual(x1) -> out (f32)  [pipelined 64x128]
    gemm_pipe64<EPI_RESID><<<dim3(1024 / 128, ROWS_ / 64), 256, 0, stream>>>(
        ffn1, W2T, b2, x1, out, ROWS_, 1024, 4096);

    (void)in_sizes; (void)n_in; (void)out_size; (void)ws_size;
}